// Round 3
// baseline (964.441 us; speedup 1.0000x reference)
//
#include <hip/hip_runtime.h>
#include <stdint.h>
#include <stddef.h>

typedef _Float16 half_t;
typedef _Float16 half2_t __attribute__((ext_vector_type(2)));
typedef _Float16 half8_t __attribute__((ext_vector_type(8)));
typedef float    floatx4 __attribute__((ext_vector_type(4)));
typedef uint32_t u32x4   __attribute__((ext_vector_type(4)));

#define SEQ_L 512
#define NBATCH 64
#define DIM 256
#define NTOT (NBATCH * SEQ_L)   // 32768 rows

// ---------- helpers ----------
__device__ __forceinline__ float fdot2f(uint32_t a, uint32_t b, float c) {
#if defined(__has_builtin)
#if __has_builtin(__builtin_amdgcn_fdot2)
  return __builtin_amdgcn_fdot2(__builtin_bit_cast(half2_t, a),
                                __builtin_bit_cast(half2_t, b), c, false);
#else
  half2_t av = __builtin_bit_cast(half2_t, a);
  half2_t bv = __builtin_bit_cast(half2_t, b);
  return c + (float)av[0] * (float)bv[0] + (float)av[1] * (float)bv[1];
#endif
#else
  half2_t av = __builtin_bit_cast(half2_t, a);
  half2_t bv = __builtin_bit_cast(half2_t, b);
  return c + (float)av[0] * (float)bv[0] + (float)av[1] * (float)bv[1];
#endif
}

__device__ __forceinline__ float sigmoidf_fast(float x) {
  return 1.0f / (1.0f + __expf(-x));
}
__device__ __forceinline__ float tanhf_fast(float x) {
  float e = __expf(2.0f * x);
  return 1.0f - 2.0f / (e + 1.0f);
}

// ---------- kernel 1: W -> f16, transposed to [768 n][256 k] ----------
__global__ void conv_w_kernel(const float* __restrict__ Wr,
                              const float* __restrict__ Wz,
                              const float* __restrict__ Wh,
                              half_t* __restrict__ Wt) {
  int n = blockIdx.x;          // 0..767
  int k = threadIdx.x;         // 0..255
  const float* W = (n < 256) ? Wr : ((n < 512) ? Wz : Wh);
  int j = n & 255;
  Wt[(size_t)n * DIM + k] = (half_t)W[(size_t)k * DIM + j];
}

// ---------- kernel 2: a = sigmoid(x@k1 - x@k2) per row ----------
__global__ __launch_bounds__(256) void attn_a_kernel(const float* __restrict__ inp,
                                                     const float* __restrict__ k1,
                                                     const float* __restrict__ k2,
                                                     float* __restrict__ a_arr) {
  int row  = blockIdx.x * 4 + (threadIdx.x >> 6);
  int lane = threadIdx.x & 63;
  const float4* x4 = (const float4*)(inp + (size_t)row * DIM);
  float4 xv  = x4[lane];
  float4 k1v = ((const float4*)k1)[lane];
  float4 k2v = ((const float4*)k2)[lane];
  float e1 = xv.x * k1v.x + xv.y * k1v.y + xv.z * k1v.z + xv.w * k1v.w;
  float e2 = xv.x * k2v.x + xv.y * k2v.y + xv.z * k2v.z + xv.w * k2v.w;
#pragma unroll
  for (int off = 32; off >= 1; off >>= 1) {
    e1 += __shfl_xor(e1, off);
    e2 += __shfl_xor(e2, off);
  }
  if (lane == 0) a_arr[row] = 1.0f / (1.0f + __expf(e2 - e1));
}

// ---------- kernel 3: P = X @ [Wr|Wz|Wh]  (MFMA f16, f32 acc, store f16) ----------
__global__ __launch_bounds__(256) void gemm_p_kernel(const float* __restrict__ X,
                                                     const half_t* __restrict__ Wt,
                                                     half_t* __restrict__ P) {
  __shared__ __align__(16) half_t As[128][32];
  __shared__ __align__(16) half_t Bs[128][32];
  const int tid  = threadIdx.x;
  const int bm   = blockIdx.x * 128;
  const int bn   = blockIdx.y * 128;
  const int lane = tid & 63;
  const int wave = tid >> 6;
  const int wm   = (wave >> 1) * 64;
  const int wn   = (wave & 1) * 64;
  const int quad = lane >> 4;
  const int l15  = lane & 15;
  const int r0   = tid >> 2;
  const int kc   = (tid & 3) * 8;

  floatx4 acc[4][4] = {};

  for (int k0 = 0; k0 < DIM; k0 += 32) {
#pragma unroll
    for (int hh = 0; hh < 2; ++hh) {
      int r = r0 + hh * 64;
      const float* asrc = X + (size_t)(bm + r) * DIM + k0 + kc;
      float4 f0 = *(const float4*)(asrc);
      float4 f1 = *(const float4*)(asrc + 4);
      half8_t av;
      av[0] = (half_t)f0.x; av[1] = (half_t)f0.y; av[2] = (half_t)f0.z; av[3] = (half_t)f0.w;
      av[4] = (half_t)f1.x; av[5] = (half_t)f1.y; av[6] = (half_t)f1.z; av[7] = (half_t)f1.w;
      *(half8_t*)(&As[r][kc]) = av;
      *(half8_t*)(&Bs[r][kc]) = *(const half8_t*)(Wt + (size_t)(bn + r) * DIM + k0 + kc);
    }
    __syncthreads();
    half8_t af[4], bf[4];
#pragma unroll
    for (int mi = 0; mi < 4; ++mi)
      af[mi] = *(const half8_t*)(&As[wm + mi * 16 + l15][quad * 8]);
#pragma unroll
    for (int ni = 0; ni < 4; ++ni)
      bf[ni] = *(const half8_t*)(&Bs[wn + ni * 16 + l15][quad * 8]);
#pragma unroll
    for (int mi = 0; mi < 4; ++mi)
#pragma unroll
      for (int ni = 0; ni < 4; ++ni)
        acc[mi][ni] = __builtin_amdgcn_mfma_f32_16x16x32_f16(af[mi], bf[ni], acc[mi][ni], 0, 0, 0);
    __syncthreads();
  }
#pragma unroll
  for (int mi = 0; mi < 4; ++mi)
#pragma unroll
    for (int ni = 0; ni < 4; ++ni) {
      int col = bn + wn + ni * 16 + l15;
#pragma unroll
      for (int rr = 0; rr < 4; ++rr) {
        int row = bm + wm + mi * 16 + quad * 4 + rr;
        P[(size_t)row * 768 + col] = (half_t)acc[mi][ni][rr];
      }
    }
}

// ---------- kernel 4: recurrence, 1024 threads/block, k-split by 4 ----------
// thread (q, j): q = tid>>8 in [0,4), j = tid&255. Owns column j over K-range
// [q*64, q*64+64). Per-thread U: 3 gates x 8 u32x4 = 96 VGPRs -> fits the
// 128-VGPR cap of __launch_bounds__(1024,4) with NO spills (the R2 killer).
// All 64 lanes of a wave share (q) -> mth reads are 64-way same-address
// broadcast (conflict-free). Partials: one float4 LDS write (q>0), epilogue
// (q==0 threads, j=0..255) reads 3x b128 and runs the gate math.
__global__ __launch_bounds__(1024, 4) void recur_kernel(
    const half_t* __restrict__ P,     // [32768, 768] f16 (xWr | xWz | xWh)
    const float* __restrict__ a_arr,  // [32768]
    const int* __restrict__ cidx,     // [32768]
    const float* __restrict__ Ur, const float* __restrict__ Uz, const float* __restrict__ Uh,
    const float* __restrict__ br, const float* __restrict__ bz, const float* __restrict__ bh,
    float* __restrict__ out) {        // [32768, 256] f32 (write-only here)
  const int b    = blockIdx.x;
  const int tid  = threadIdx.x;
  const int j    = tid & 255;
  const int q    = tid >> 8;          // 0..3
  const int koff = q * 64;            // in halves

  __shared__ __align__(16) half_t hist[SEQ_L][128];   // 128 KB: h[i][128..255] f16
  __shared__ __align__(16) half_t mth[DIM];           // 512 B broadcast buffer
  __shared__ __align__(16) floatx4 part[3][DIM];      // 12 KB: partials q=1..3

  // ---- register-resident U slice (packed f16 pairs, u32x4 granularity) ----
  u32x4 ur4[8], uz4[8], uh4[8];
#pragma unroll
  for (int c8 = 0; c8 < 8; ++c8) {
#pragma unroll
    for (int t = 0; t < 4; ++t) {
      const int k = koff + c8 * 8 + t * 2;
      half2_t tr, tz, th;
      tr[0] = (half_t)Ur[(size_t)(k + 0) * DIM + j];
      tr[1] = (half_t)Ur[(size_t)(k + 1) * DIM + j];
      tz[0] = (half_t)Uz[(size_t)(k + 0) * DIM + j];
      tz[1] = (half_t)Uz[(size_t)(k + 1) * DIM + j];
      th[0] = (half_t)Uh[(size_t)(k + 0) * DIM + j];
      th[1] = (half_t)Uh[(size_t)(k + 1) * DIM + j];
      ur4[c8][t] = __builtin_bit_cast(uint32_t, tr);
      uz4[c8][t] = __builtin_bit_cast(uint32_t, tz);
      uh4[c8][t] = __builtin_bit_cast(uint32_t, th);
    }
  }
  const float brj = br[j], bzj = bz[j], bhj = bh[j];

  // step 0 has mt == 0 (h0 = 0, c0 = 0)
  if (tid < 128) ((uint32_t*)mth)[tid] = 0u;
  __syncthreads();

  float h   = 0.0f;   // q==0 thread j: h[j] (f32)
  float mtj = 0.0f;   // q==0 thread j: mt[j] for current step (f32)
  const int base = b * SEQ_L;

  for (int i = 0; i < SEQ_L; ++i) {
    // early loads: hidden under the dot loop
    float pr = 0.f, pz = 0.f, ph = 0.f;
    if (q == 0) {
      const half_t* prow = P + (size_t)(base + i) * 768;
      pr = (float)prow[j];
      pz = (float)prow[DIM + j];
      ph = (float)prow[2 * DIM + j];
    }
    const int   inext  = (i < SEQ_L - 1) ? (i + 1) : (SEQ_L - 1);
    const float a_next = a_arr[base + inext];   // uniform -> scalar
    const int   c_next = cidx[base + inext];    // uniform -> scalar

    // ---- partial dots over this thread's 64-wide K-range ----
    float accr = 0.0f, accz = 0.0f, acch = 0.0f;
    const u32x4* mq = (const u32x4*)(mth + koff);
#pragma unroll
    for (int c8 = 0; c8 < 8; ++c8) {
      u32x4 m4 = mq[c8];                // ds_read_b128, 64-way broadcast
      accr = fdot2f(m4.x, ur4[c8][0], accr);
      accz = fdot2f(m4.x, uz4[c8][0], accz);
      acch = fdot2f(m4.x, uh4[c8][0], acch);
      accr = fdot2f(m4.y, ur4[c8][1], accr);
      accz = fdot2f(m4.y, uz4[c8][1], accz);
      acch = fdot2f(m4.y, uh4[c8][1], acch);
      accr = fdot2f(m4.z, ur4[c8][2], accr);
      accz = fdot2f(m4.z, uz4[c8][2], accz);
      acch = fdot2f(m4.z, uh4[c8][2], acch);
      accr = fdot2f(m4.w, ur4[c8][3], accr);
      accz = fdot2f(m4.w, uz4[c8][3], accz);
      acch = fdot2f(m4.w, uh4[c8][3], acch);
    }
    if (q > 0) {
      floatx4 p;
      p[0] = accr; p[1] = accz; p[2] = acch; p[3] = 0.0f;
      part[q - 1][j] = p;               // ds_write_b128, contiguous
    }
    __syncthreads();   // partials visible; all mth(i) reads complete

    if (q == 0) {
      floatx4 p0 = part[0][j];
      floatx4 p1 = part[1][j];
      floatx4 p2 = part[2][j];
      accr += p0[0] + p1[0] + p2[0];
      accz += p0[1] + p1[1] + p2[1];
      acch += p0[2] + p1[2] + p2[2];
      const float rg = sigmoidf_fast(pr + brj + accr);
      const float zg = sigmoidf_fast(pz + bzj + accz);
      const float hb = tanhf_fast(ph + bhj + rg * acch);
      h = (1.0f - zg) * mtj + zg * hb;
      out[(size_t)(base + i) * DIM + j] = h;
      if (j >= 128) hist[i][j - 128] = (half_t)h;
      // next step's mt: all inputs owned by this thread
      float mtn;
      if (j < 128) {
        mtn = a_next * h;
      } else {
        float coref = (c_next > 0) ? (float)hist[c_next - 1][j - 128] : 0.0f;
        mtn = (1.0f - a_next) * coref;
      }
      mtj = mtn;
      mth[j] = (half_t)mtn;
    }
    __syncthreads();   // mth(i+1) + hist(i) visible before next phase A
  }
}

// ---------- launcher ----------
extern "C" void kernel_launch(void* const* d_in, const int* in_sizes, int n_in,
                              void* d_out, int out_size, void* d_ws, size_t ws_size,
                              hipStream_t stream) {
  const float* inp = (const float*)d_in[0];
  const int*   ci  = (const int*)d_in[1];
  const float* Wr  = (const float*)d_in[2];
  const float* br  = (const float*)d_in[3];
  const float* Ur  = (const float*)d_in[4];
  const float* Wz  = (const float*)d_in[5];
  const float* bz  = (const float*)d_in[6];
  const float* Uz  = (const float*)d_in[7];
  const float* Wh  = (const float*)d_in[8];
  const float* bh  = (const float*)d_in[9];
  const float* Uh  = (const float*)d_in[10];
  const float* k1  = (const float*)d_in[11];
  const float* k2  = (const float*)d_in[12];
  float* out = (float*)d_out;

  char* ws = (char*)d_ws;
  // ws carve: Wt [768*256 f16] | P [32768*768 f16] | a [32768 f32]
  half_t* Wt    = (half_t*)ws;
  half_t* P     = (half_t*)(ws + 393216);
  float*  a_arr = (float*)(ws + 393216 + 50331648);

  conv_w_kernel<<<dim3(768), dim3(256), 0, stream>>>(Wr, Wz, Wh, Wt);
  attn_a_kernel<<<dim3(NTOT / 4), dim3(256), 0, stream>>>(inp, k1, k2, a_arr);
  gemm_p_kernel<<<dim3(NTOT / 128, 6), dim3(256), 0, stream>>>(inp, Wt, P);
  recur_kernel<<<dim3(NBATCH), dim3(1024), 0, stream>>>(P, a_arr, ci, Ur, Uz, Uh,
                                                        br, bz, bh, out);
}

// Round 4
// 801.066 us; speedup vs baseline: 1.2039x; 1.2039x over previous
//
#include <hip/hip_runtime.h>
#include <stdint.h>
#include <stddef.h>

typedef _Float16 half_t;
typedef _Float16 half2_t __attribute__((ext_vector_type(2)));
typedef _Float16 half8_t __attribute__((ext_vector_type(8)));
typedef float    floatx4 __attribute__((ext_vector_type(4)));
typedef uint32_t u32x4   __attribute__((ext_vector_type(4)));

#define SEQ_L 512
#define NBATCH 64
#define DIM 256
#define NTOT (NBATCH * SEQ_L)   // 32768 rows

// ---------- helpers ----------
__device__ __forceinline__ float fdot2f(uint32_t a, uint32_t b, float c) {
#if defined(__has_builtin)
#if __has_builtin(__builtin_amdgcn_fdot2)
  return __builtin_amdgcn_fdot2(__builtin_bit_cast(half2_t, a),
                                __builtin_bit_cast(half2_t, b), c, false);
#else
  half2_t av = __builtin_bit_cast(half2_t, a);
  half2_t bv = __builtin_bit_cast(half2_t, b);
  return c + (float)av[0] * (float)bv[0] + (float)av[1] * (float)bv[1];
#endif
#else
  half2_t av = __builtin_bit_cast(half2_t, a);
  half2_t bv = __builtin_bit_cast(half2_t, b);
  return c + (float)av[0] * (float)bv[0] + (float)av[1] * (float)bv[1];
#endif
}

__device__ __forceinline__ float sigmoidf_fast(float x) {
  return 1.0f / (1.0f + __expf(-x));
}
__device__ __forceinline__ float tanhf_fast(float x) {
  float e = __expf(2.0f * x);
  return 1.0f - 2.0f / (e + 1.0f);
}

// ---------- kernel 1: W -> f16, transposed to [768 n][256 k] ----------
__global__ void conv_w_kernel(const float* __restrict__ Wr,
                              const float* __restrict__ Wz,
                              const float* __restrict__ Wh,
                              half_t* __restrict__ Wt) {
  int n = blockIdx.x;          // 0..767
  int k = threadIdx.x;         // 0..255
  const float* W = (n < 256) ? Wr : ((n < 512) ? Wz : Wh);
  int j = n & 255;
  Wt[(size_t)n * DIM + k] = (half_t)W[(size_t)k * DIM + j];
}

// ---------- kernel 2: a = sigmoid(x@k1 - x@k2) per row ----------
__global__ __launch_bounds__(256) void attn_a_kernel(const float* __restrict__ inp,
                                                     const float* __restrict__ k1,
                                                     const float* __restrict__ k2,
                                                     float* __restrict__ a_arr) {
  int row  = blockIdx.x * 4 + (threadIdx.x >> 6);
  int lane = threadIdx.x & 63;
  const float4* x4 = (const float4*)(inp + (size_t)row * DIM);
  float4 xv  = x4[lane];
  float4 k1v = ((const float4*)k1)[lane];
  float4 k2v = ((const float4*)k2)[lane];
  float e1 = xv.x * k1v.x + xv.y * k1v.y + xv.z * k1v.z + xv.w * k1v.w;
  float e2 = xv.x * k2v.x + xv.y * k2v.y + xv.z * k2v.z + xv.w * k2v.w;
#pragma unroll
  for (int off = 32; off >= 1; off >>= 1) {
    e1 += __shfl_xor(e1, off);
    e2 += __shfl_xor(e2, off);
  }
  if (lane == 0) a_arr[row] = 1.0f / (1.0f + __expf(e2 - e1));
}

// ---------- kernel 3: P = X @ [Wr|Wz|Wh]  (MFMA f16, f32 acc, store f16) ----------
__global__ __launch_bounds__(256) void gemm_p_kernel(const float* __restrict__ X,
                                                     const half_t* __restrict__ Wt,
                                                     half_t* __restrict__ P) {
  __shared__ __align__(16) half_t As[128][32];
  __shared__ __align__(16) half_t Bs[128][32];
  const int tid  = threadIdx.x;
  const int bm   = blockIdx.x * 128;
  const int bn   = blockIdx.y * 128;
  const int lane = tid & 63;
  const int wave = tid >> 6;
  const int wm   = (wave >> 1) * 64;
  const int wn   = (wave & 1) * 64;
  const int quad = lane >> 4;
  const int l15  = lane & 15;
  const int r0   = tid >> 2;
  const int kc   = (tid & 3) * 8;

  floatx4 acc[4][4] = {};

  for (int k0 = 0; k0 < DIM; k0 += 32) {
#pragma unroll
    for (int hh = 0; hh < 2; ++hh) {
      int r = r0 + hh * 64;
      const float* asrc = X + (size_t)(bm + r) * DIM + k0 + kc;
      float4 f0 = *(const float4*)(asrc);
      float4 f1 = *(const float4*)(asrc + 4);
      half8_t av;
      av[0] = (half_t)f0.x; av[1] = (half_t)f0.y; av[2] = (half_t)f0.z; av[3] = (half_t)f0.w;
      av[4] = (half_t)f1.x; av[5] = (half_t)f1.y; av[6] = (half_t)f1.z; av[7] = (half_t)f1.w;
      *(half8_t*)(&As[r][kc]) = av;
      *(half8_t*)(&Bs[r][kc]) = *(const half8_t*)(Wt + (size_t)(bn + r) * DIM + k0 + kc);
    }
    __syncthreads();
    half8_t af[4], bf[4];
#pragma unroll
    for (int mi = 0; mi < 4; ++mi)
      af[mi] = *(const half8_t*)(&As[wm + mi * 16 + l15][quad * 8]);
#pragma unroll
    for (int ni = 0; ni < 4; ++ni)
      bf[ni] = *(const half8_t*)(&Bs[wn + ni * 16 + l15][quad * 8]);
#pragma unroll
    for (int mi = 0; mi < 4; ++mi)
#pragma unroll
      for (int ni = 0; ni < 4; ++ni)
        acc[mi][ni] = __builtin_amdgcn_mfma_f32_16x16x32_f16(af[mi], bf[ni], acc[mi][ni], 0, 0, 0);
    __syncthreads();
  }
#pragma unroll
  for (int mi = 0; mi < 4; ++mi)
#pragma unroll
    for (int ni = 0; ni < 4; ++ni) {
      int col = bn + wn + ni * 16 + l15;
#pragma unroll
      for (int rr = 0; rr < 4; ++rr) {
        int row = bm + wm + mi * 16 + quad * 4 + rr;
        P[(size_t)row * 768 + col] = (half_t)acc[mi][ni][rr];
      }
    }
}

// ---------- kernel 4: recurrence, 512 threads, k-split 2, FULL register budget ----------
// __launch_bounds__(512, 1): observed toolchain semantics = min 1 BLOCK/CU ->
// 8 waves/CU -> 2 waves/EU -> 256 VGPR/thread budget. Demand ~230 (192 packed-U
// + working) fits in pure arch VGPRs: no AGPR copies, no scratch (the R1-R3 killer).
// Out-stores buffered in an LDS ring, flushed by half-1 waves every 8 steps to
// amortize the vmcnt(0) store-drain at s_barrier.
__global__ __launch_bounds__(512, 1) void recur_kernel(
    const half_t* __restrict__ P,     // [32768, 768] f16 (xWr | xWz | xWh)
    const float* __restrict__ a_arr,  // [32768]
    const int* __restrict__ cidx,     // [32768]
    const float* __restrict__ Ur, const float* __restrict__ Uz, const float* __restrict__ Uh,
    const float* __restrict__ br, const float* __restrict__ bz, const float* __restrict__ bh,
    float* __restrict__ out) {        // [32768, 256] f32
  const int tid  = threadIdx.x;
  const int j    = tid & 255;
  const int half = tid >> 8;          // 0 or 1
  const int koff = half * 128;        // in half-elements

  __shared__ __align__(16) half_t hist[SEQ_L][128];   // 128 KB: h[i][128..255] f16
  __shared__ __align__(16) half_t mth[DIM];           // 512 B broadcast buffer
  __shared__ float part[3][DIM];                      // 3 KB: half-1 partials
  __shared__ __align__(16) float ring[16][DIM];       // 16 KB: out staging ring

  // ---- register-resident U half-columns (packed f16 pairs) ----
  u32x4 ur4[16], uz4[16], uh4[16];
#pragma unroll
  for (int q = 0; q < 16; ++q) {
#pragma unroll
    for (int t = 0; t < 4; ++t) {
      const int k = koff + q * 8 + t * 2;
      half2_t tr, tz, th;
      tr[0] = (half_t)Ur[(size_t)(k + 0) * DIM + j];
      tr[1] = (half_t)Ur[(size_t)(k + 1) * DIM + j];
      tz[0] = (half_t)Uz[(size_t)(k + 0) * DIM + j];
      tz[1] = (half_t)Uz[(size_t)(k + 1) * DIM + j];
      th[0] = (half_t)Uh[(size_t)(k + 0) * DIM + j];
      th[1] = (half_t)Uh[(size_t)(k + 1) * DIM + j];
      ur4[q][t] = __builtin_bit_cast(uint32_t, tr);
      uz4[q][t] = __builtin_bit_cast(uint32_t, tz);
      uh4[q][t] = __builtin_bit_cast(uint32_t, th);
    }
  }
  const float brj = br[j], bzj = bz[j], bhj = bh[j];

  // step 0 has mt == 0 (h0 = 0, c0 = 0)
  if (tid < 128) ((uint32_t*)mth)[tid] = 0u;
  __syncthreads();

  float h   = 0.0f;   // half-0 thread j: h[j]
  float mtj = 0.0f;   // half-0 thread j: current step's mt[j] (f32)
  const int base = blockIdx.x * SEQ_L;

  for (int i = 0; i < SEQ_L; ++i) {
    // early loads, hidden under the dot loop
    float pr = 0.f, pz = 0.f, ph = 0.f;
    if (half == 0) {
      const half_t* prow = P + (size_t)(base + i) * 768;
      pr = (float)prow[j];
      pz = (float)prow[DIM + j];
      ph = (float)prow[2 * DIM + j];
    }
    const int   inext  = (i < SEQ_L - 1) ? (i + 1) : (SEQ_L - 1);
    const float a_next = a_arr[base + inext];   // uniform -> scalar
    const int   c_next = cidx[base + inext];    // uniform -> scalar

    // ---- dots over this thread's 128-element K-half ----
    float accr = 0.0f, accz = 0.0f, acch = 0.0f;
    const u32x4* mq = (const u32x4*)(mth + koff);
#pragma unroll
    for (int q = 0; q < 16; ++q) {
      u32x4 m4 = mq[q];                 // ds_read_b128, 64-way broadcast
      accr = fdot2f(m4.x, ur4[q][0], accr);
      accz = fdot2f(m4.x, uz4[q][0], accz);
      acch = fdot2f(m4.x, uh4[q][0], acch);
      accr = fdot2f(m4.y, ur4[q][1], accr);
      accz = fdot2f(m4.y, uz4[q][1], accz);
      acch = fdot2f(m4.y, uh4[q][1], acch);
      accr = fdot2f(m4.z, ur4[q][2], accr);
      accz = fdot2f(m4.z, uz4[q][2], accz);
      acch = fdot2f(m4.z, uh4[q][2], acch);
      accr = fdot2f(m4.w, ur4[q][3], accr);
      accz = fdot2f(m4.w, uz4[q][3], accz);
      acch = fdot2f(m4.w, uh4[q][3], acch);
    }
    if (half == 1) {
      part[0][j] = accr;
      part[1][j] = accz;
      part[2][j] = acch;
    }
    __syncthreads();   // B1: partials visible; mth(i) reads complete

    if (half == 0) {
      accr += part[0][j];
      accz += part[1][j];
      acch += part[2][j];
      const float rg = sigmoidf_fast(pr + brj + accr);
      const float zg = sigmoidf_fast(pz + bzj + accz);
      const float hb = tanhf_fast(ph + bhj + rg * acch);
      h = (1.0f - zg) * mtj + zg * hb;
      ring[i & 15][j] = h;               // LDS staging (no global store here)
      if (j >= 128) hist[i][j - 128] = (half_t)h;
      float mtn;
      if (j < 128) {
        mtn = a_next * h;
      } else {
        // c_next-1 may equal i: same-thread LDS write->read is in-order, safe
        float coref = (c_next > 0) ? (float)hist[c_next - 1][j - 128] : 0.0f;
        mtn = (1.0f - a_next) * coref;
      }
      mtj = mtn;
      mth[j] = (half_t)mtn;
    } else {
      // half-1 waves: flush 8 completed ring rows every 8 steps
      if ((i & 7) == 0 && i > 0) {
        const int t1 = j;                // 0..255
#pragma unroll
        for (int rr = 0; rr < 8; ++rr) {
          const int row = i - 8 + rr;
          out[(size_t)(base + row) * DIM + t1] = ring[row & 15][t1];
        }
      }
    }
    __syncthreads();   // B2: mth(i+1) + hist(i) visible before next dot phase
  }

  // tail: rows 504..511 still in the ring
#pragma unroll
  for (int rr = 0; rr < 4; ++rr) {
    const int idx = rr * 512 + tid;     // 0..2047
    const int row = 504 + (idx >> 8);
    const int col = idx & 255;
    out[(size_t)(base + row) * DIM + col] = ring[row & 15][col];
  }
}

// ---------- launcher ----------
extern "C" void kernel_launch(void* const* d_in, const int* in_sizes, int n_in,
                              void* d_out, int out_size, void* d_ws, size_t ws_size,
                              hipStream_t stream) {
  const float* inp = (const float*)d_in[0];
  const int*   ci  = (const int*)d_in[1];
  const float* Wr  = (const float*)d_in[2];
  const float* br  = (const float*)d_in[3];
  const float* Ur  = (const float*)d_in[4];
  const float* Wz  = (const float*)d_in[5];
  const float* bz  = (const float*)d_in[6];
  const float* Uz  = (const float*)d_in[7];
  const float* Wh  = (const float*)d_in[8];
  const float* bh  = (const float*)d_in[9];
  const float* Uh  = (const float*)d_in[10];
  const float* k1  = (const float*)d_in[11];
  const float* k2  = (const float*)d_in[12];
  float* out = (float*)d_out;

  char* ws = (char*)d_ws;
  // ws carve: Wt [768*256 f16] | P [32768*768 f16] | a [32768 f32]
  half_t* Wt    = (half_t*)ws;
  half_t* P     = (half_t*)(ws + 393216);
  float*  a_arr = (float*)(ws + 393216 + 50331648);

  conv_w_kernel<<<dim3(768), dim3(256), 0, stream>>>(Wr, Wz, Wh, Wt);
  attn_a_kernel<<<dim3(NTOT / 4), dim3(256), 0, stream>>>(inp, k1, k2, a_arr);
  gemm_p_kernel<<<dim3(NTOT / 128, 6), dim3(256), 0, stream>>>(inp, Wt, P);
  recur_kernel<<<dim3(NBATCH), dim3(512), 0, stream>>>(P, a_arr, ci, Ur, Uz, Uh,
                                                       br, bz, bh, out);
}